// Round 9
// baseline (178.152 us; speedup 1.0000x reference)
//
#include <hip/hip_runtime.h>
#include <hip/hip_bf16.h>
#include <stdint.h>

#define D 128
#define CAP 32        // per-node slot capacity; Poisson(12.8): P(deg>32)~1e-6/node,
                      // expected <2 nodes overflow on E=640K -- k_ovf covers them.
#define OVFCAP 65536

using bf16x8 = __attribute__((ext_vector_type(8))) short;
using f32x4  = __attribute__((ext_vector_type(4))) float;
using u32x4  = __attribute__((ext_vector_type(4))) unsigned int;

__device__ __forceinline__ unsigned short f2bf(float f) {
    unsigned u = __float_as_uint(f);
    u = (u + 0x7fffu + ((u >> 16) & 1u)) >> 16;   // RNE
    return (unsigned short)u;
}
__device__ __forceinline__ float bf2f(unsigned short h) {
    return __uint_as_float(((unsigned)h) << 16);
}

__device__ __forceinline__ bf16x8 cvt8(float4 a, float4 b) {
    union { bf16x8 v; __hip_bfloat162 h[4]; } u;
    u.h[0] = __float22bfloat162_rn(make_float2(a.x, a.y));
    u.h[1] = __float22bfloat162_rn(make_float2(a.z, a.w));
    u.h[2] = __float22bfloat162_rn(make_float2(b.x, b.y));
    u.h[3] = __float22bfloat162_rn(make_float2(b.z, b.w));
    return u.v;
}

__device__ __forceinline__ u32x4 pack2(f32x4 x, f32x4 y) {
    union { u32x4 u; __hip_bfloat162 h[4]; } o;
    o.h[0] = __float22bfloat162_rn(make_float2(x[0], x[1]));
    o.h[1] = __float22bfloat162_rn(make_float2(x[2], x[3]));
    o.h[2] = __float22bfloat162_rn(make_float2(y[0], y[1]));
    o.h[3] = __float22bfloat162_rn(make_float2(y[2], y[3]));
    return o.u;
}

// ---------- zero deg/ovf counter (prep3's featb/Wt passes eliminated:
// transform now reads feat/W directly -- saves ~40MB of HBM traffic) ----------
__global__ __launch_bounds__(256) void k_zero(int* __restrict__ deg, int N)
{
    int i = blockIdx.x * 256 + threadIdx.x;
    if (i <= N) deg[i] = 0;
}

// ---------- fused3: transform + count&slot-write, Bresenham-interleaved ----------
// transform: H[r][n][perm(c)] = bf16(feat[n][:] @ W[r]). W[rel] (fp32,
// L2-resident) is transposed+converted straight into the XOR-swizzled LDS
// (coalesced float4-pair reads, packed b32 writes, same verified layout);
// B-frags read fp32 feat directly (L3-resident after first touch) and
// convert in-register. One barrier, conflict-free ds_read_b128, permuted
// sector-aligned u32x4 stores. count (r0-champion config: plain stores,
// 1 edge/thread): ord = atomicAdd(deg[dst]); slots[dst*CAP+ord] = key.
__global__ __launch_bounds__(256) void fused3_kernel(
    const float* __restrict__ feat, const float* __restrict__ W,
    unsigned short* __restrict__ H,
    const int* __restrict__ dst, const int* __restrict__ et,
    const int* __restrict__ src,
    int* __restrict__ deg, unsigned int* __restrict__ slots,
    int* __restrict__ ovf,
    int N, int NBX, int tBlocks, int cntBlocks, int E)
{
    __shared__ __align__(16) unsigned short sW[128 * 128];   // 32 KB
    const int b = blockIdx.x;
    const long long total = (long long)tBlocks + cntBlocks;

    long long cb = ((long long)b * cntBlocks) / total;
    bool isCount = (((long long)(b + 1) * cntBlocks) / total) > cb;

    if (isCount) {
        int e = (int)cb * 256 + threadIdx.x;
        if (e < E) {
            int d = dst[e];
            unsigned key = ((unsigned)et[e] * (unsigned)N + (unsigned)src[e]) << 8;
            int ord = atomicAdd(&deg[d], 1);
            if (ord < CAP) {
                slots[(size_t)d * CAP + ord] = key;
            } else {
                int o = atomicAdd(&deg[N], 1);   // overflow counter
                if (o < OVFCAP) ovf[o] = e;
            }
        }
        return;
    }

    const int tIdx = b - (int)cb;
    const int rel = tIdx / NBX;
    const int bx  = tIdx - rel * NBX;
    const int tid  = threadIdx.x;
    const int wave = tid >> 6, lane = tid & 63;
    const int q    = lane >> 4, mlo = lane & 15;

    // stage W[rel] (fp32 [k][c]) -> sW bf16 [c][k], 16B-chunk XOR swizzle:
    // element (k,c) chunk ch=k>>3 lands at byte 2*(c*128 + ((ch^(c&15))<<3)+(k&7)).
    // Pack k/k+1 pairs -> one b32 write; reads are coalesced float4 rows.
    {
        const float* wsrc = W + ((size_t)rel << 14);
        #pragma unroll
        for (int i = 0; i < 8; ++i) {
            int q4 = tid + 256 * i;          // 0..2047 float4-groups
            int k2 = q4 >> 5;                // k-pair index, k = 2*k2
            int c4 = (q4 & 31) << 2;         // base channel
            float4 fa = *(const float4*)(wsrc + ((size_t)k2 << 8) + c4);
            float4 fb = *(const float4*)(wsrc + ((size_t)k2 << 8) + 128 + c4);
            const float* fav = (const float*)&fa;
            const float* fbv = (const float*)&fb;
            #pragma unroll
            for (int cc = 0; cc < 4; ++cc) {
                int c = c4 + cc;
                __hip_bfloat162 pv = __float22bfloat162_rn(
                    make_float2(fav[cc], fbv[cc]));
                int ch = k2 >> 2;
                int off = c * 128 + (((ch ^ (c & 15)) << 3) + ((k2 & 3) << 1));
                *(unsigned*)&sW[off] = *(unsigned*)&pv;
            }
        }
    }

    // B-frags from fp32 feat (cvt in-register): 2 groups of 16 nodes;
    // B[k=ks*32+q*8+j][n=mlo]
    const int nb = bx * 128 + wave * 32;
    bf16x8 bfr[2][4];
    int nodeg[2];
    #pragma unroll
    for (int g = 0; g < 2; ++g) {
        int node = nb + g * 16 + mlo;
        nodeg[g] = node;
        int ld = node < N ? node : N - 1;
        const float* fp = feat + (size_t)ld * D + q * 8;
        #pragma unroll
        for (int ks = 0; ks < 4; ++ks) {
            const float4* pp = (const float4*)(fp + ks * 32);
            bfr[g][ks] = cvt8(pp[0], pp[1]);
        }
    }
    __syncthreads();

    const size_t Hb = (size_t)rel * N * D;
    unsigned short* hp0 = H + Hb + (size_t)nodeg[0] * D + q * 8;
    unsigned short* hp1 = H + Hb + (size_t)nodeg[1] * D + q * 8;

    #pragma unroll
    for (int j = 0; j < 4; ++j) {
        bf16x8 af0[4], af1[4];
        const int row0 = (2 * j) * 16 + mlo, row1 = row0 + 16;
        #pragma unroll
        for (int ks = 0; ks < 4; ++ks) {
            af0[ks] = *(const bf16x8*)&sW[row0 * 128 + (((ks * 4 + q) ^ mlo) * 8)];
            af1[ks] = *(const bf16x8*)&sW[row1 * 128 + (((ks * 4 + q) ^ mlo) * 8)];
        }
        #pragma unroll
        for (int g = 0; g < 2; ++g) {
            f32x4 a = {0.f,0.f,0.f,0.f}, c = {0.f,0.f,0.f,0.f};
            #pragma unroll
            for (int ks = 0; ks < 4; ++ks) {
                a = __builtin_amdgcn_mfma_f32_16x16x32_bf16(af0[ks], bfr[g][ks], a, 0, 0, 0);
                c = __builtin_amdgcn_mfma_f32_16x16x32_bf16(af1[ks], bfr[g][ks], c, 0, 0, 0);
            }
            if (nodeg[g] < N)
                *(u32x4*)((g ? hp1 : hp0) + j * 32) = pack2(a, c);
        }
    }
}

// ---------- gather: 1 node/wave; CAP=32 -> exactly one 16-load batch.
// Head loads (feat residual, slots row, deg) issued back-to-back with static
// lane clamp so they resolve in parallel. 8-B lane loads (32 lanes/row,
// halves take even/odd edges); combine via shfl(lane^32); channel map
// matches transform's permuted H layout. ----------
__global__ __launch_bounds__(256) void k_gather6(
    const char* __restrict__ Hc, const unsigned int* __restrict__ slots,
    const int* __restrict__ deg, const float* __restrict__ feat,
    float* __restrict__ out, int N)
{
    int n = blockIdx.x * 4 + (threadIdx.x >> 6);
    if (n >= N) return;
    int lane = threadIdx.x & 63;
    int h = lane >> 5, l5 = lane & 31;

    // --- independent head loads, all issued before any dependent op ---
    const int f4 = 8 * (l5 >> 3) + 4 * (l5 & 1) + ((l5 >> 1) & 3);
    float4 fv = ((const float4*)feat)[(size_t)n * 32 + f4];   // h=1 hits same lines
    unsigned ep = slots[(size_t)n * CAP + (lane < CAP ? lane : CAP - 1)];
    int dg = deg[n];

    dg = __builtin_amdgcn_readfirstlane(dg);
    int capped = dg < CAP ? dg : CAP;

    float2 acc0 = {0.f, 0.f}, acc1 = {0.f, 0.f};

    if (capped > 0) {
        unsigned long long a[16];
        #pragma unroll
        for (int u = 0; u < 16; ++u) {
            int eidx = 2 * u + h;
            int cl = eidx < capped ? eidx : capped - 1;
            unsigned p = __shfl(ep, cl);
            a[u] = *(const unsigned long long*)(Hc + p + l5 * 8);
        }
        #pragma unroll
        for (int u = 0; u < 16; ++u) {
            bool v = (2 * u + h) < capped;
            unsigned lo = (unsigned)a[u], hi = (unsigned)(a[u] >> 32);
            acc0.x += v ? bf2f((unsigned short)(lo & 0xffffu)) : 0.f;
            acc0.y += v ? bf2f((unsigned short)(lo >> 16)) : 0.f;
            acc1.x += v ? bf2f((unsigned short)(hi & 0xffffu)) : 0.f;
            acc1.y += v ? bf2f((unsigned short)(hi >> 16)) : 0.f;
        }
    }
    // combine halves
    acc0.x += __shfl(acc0.x, lane ^ 32);
    acc0.y += __shfl(acc0.y, lane ^ 32);
    acc1.x += __shfl(acc1.x, lane ^ 32);
    acc1.y += __shfl(acc1.y, lane ^ 32);
    if (h == 0) {
        float4 o;
        o.x = fv.x + acc0.x; o.y = fv.y + acc0.y;
        o.z = fv.z + acc1.x; o.w = fv.w + acc1.y;
        ((float4*)out)[(size_t)n * 32 + f4] = o;
    }
}

// ---------- overflow scatter (tiny: deg>CAP nodes only; correctness path) ----------
__global__ __launch_bounds__(256) void k_ovf(
    const char* __restrict__ Hc, const int* __restrict__ ovf,
    const int* __restrict__ deg /* deg[N] = count */,
    const int* __restrict__ dst, const int* __restrict__ et,
    const int* __restrict__ src, float* __restrict__ out, int N)
{
    int cnt = deg[N];
    if (cnt > OVFCAP) cnt = OVFCAP;
    int wid = (blockIdx.x * 256 + threadIdx.x) >> 6;
    int nw = (gridDim.x * 256) >> 6;
    int lane = threadIdx.x & 63;
    const int jj = lane >> 4, qq = (lane >> 2) & 3, pp = lane & 3;
    const int f = 16 * jj + 8 * (pp >> 1) + 2 * qq + (pp & 1);
    for (int i = wid; i < cnt; i += nw) {
        int e = ovf[i];
        int d = dst[e];
        unsigned key = ((unsigned)et[e] * (unsigned)N + (unsigned)src[e]) << 8;
        unsigned a = *(const unsigned*)(Hc + key + lane * 4);
        atomicAdd(out + (size_t)d * D + 2 * f,     bf2f((unsigned short)(a & 0xffffu)));
        atomicAdd(out + (size_t)d * D + 2 * f + 1, bf2f((unsigned short)(a >> 16)));
    }
}

// ---------- fallbacks ----------
__global__ __launch_bounds__(256) void init_kernel(
    const float* __restrict__ feat, float* __restrict__ out, int n4)
{
    int i = blockIdx.x * 256 + threadIdx.x;
    if (i < n4) ((float4*)out)[i] = ((const float4*)feat)[i];
}

__global__ __launch_bounds__(128) void edge_matvec_kernel(
    const float* __restrict__ feat, const float* __restrict__ W,
    const int* __restrict__ et, const int* __restrict__ src,
    const int* __restrict__ dst, float* __restrict__ out, int E)
{
    __shared__ float xs[D];
    int e = blockIdx.x;
    int c = threadIdx.x;
    int s = src[e], r = et[e], d = dst[e];
    xs[c] = feat[(size_t)s * D + c];
    __syncthreads();
    const float* Wr = W + (size_t)r * D * D;
    float acc = 0.f;
    #pragma unroll 8
    for (int k = 0; k < D; ++k) acc += xs[k] * Wr[(size_t)k * D + c];
    atomicAdd(out + (size_t)d * D + c, acc);
}

static inline size_t al256(size_t x) { return (x + 255) & ~(size_t)255; }

extern "C" void kernel_launch(void* const* d_in, const int* in_sizes, int n_in,
                              void* d_out, int out_size, void* d_ws, size_t ws_size,
                              hipStream_t stream) {
    const float* feat = (const float*)d_in[0];
    const float* W    = (const float*)d_in[1];
    const int*   et   = (const int*)d_in[2];
    const int*   src  = (const int*)d_in[3];
    const int*   dst  = (const int*)d_in[4];
    float* out = (float*)d_out;

    const int N = in_sizes[0] / D;
    const int R = in_sizes[1] / (D * D);
    const int E = in_sizes[2];

    size_t hB   = al256((size_t)R * N * D * sizeof(unsigned short));
    size_t degB = al256((size_t)(N + 1) * sizeof(int));
    size_t sltB = al256((size_t)N * CAP * sizeof(unsigned int));
    size_t ovfB = al256((size_t)OVFCAP * sizeof(int));
    size_t need = hB + degB + sltB + ovfB;

    const bool packable = ((size_t)R * (size_t)N * 256ull <= 0xFFFFFFFFull);

    if (ws_size >= need && packable) {
        char* p = (char*)d_ws;
        unsigned short* H      = (unsigned short*)p;           p += hB;
        int*            deg    = (int*)p;                      p += degB;
        unsigned int*   slots  = (unsigned int*)p;             p += sltB;
        int*            ovf    = (int*)p;

        int zBlocks  = (N + 1 + 255) / 256;
        int cntBlocks = (E + 255) / 256;

        k_zero<<<zBlocks, 256, 0, stream>>>(deg, N);

        int NBX = (N + 127) / 128;
        int tBlocks = NBX * R;
        fused3_kernel<<<tBlocks + cntBlocks, 256, 0, stream>>>(
            feat, W, H, dst, et, src, deg, slots, ovf,
            N, NBX, tBlocks, cntBlocks, E);

        k_gather6<<<(N + 3) / 4, 256, 0, stream>>>(
            (const char*)H, slots, deg, feat, out, N);

        k_ovf<<<16, 256, 0, stream>>>(
            (const char*)H, ovf, deg, dst, et, src, out, N);
    } else {
        int n4 = (N * D) / 4;
        init_kernel<<<(n4 + 255) / 256, 256, 0, stream>>>(feat, out, n4);
        edge_matvec_kernel<<<E, 128, 0, stream>>>(feat, W, et, src, dst, out, E);
    }
}

// Round 10
// 169.237 us; speedup vs baseline: 1.0527x; 1.0527x over previous
//
#include <hip/hip_runtime.h>
#include <hip/hip_bf16.h>
#include <stdint.h>

#define D 128
#define CAP 32        // per-node slot capacity; Poisson(12.8): P(deg>32)~1e-6/node,
                      // expected <2 nodes overflow on E=640K -- k_ovf covers them.
#define OVFCAP 65536

using bf16x8 = __attribute__((ext_vector_type(8))) short;
using f32x4  = __attribute__((ext_vector_type(4))) float;
using u32x4  = __attribute__((ext_vector_type(4))) unsigned int;

__device__ __forceinline__ unsigned short f2bf(float f) {
    unsigned u = __float_as_uint(f);
    u = (u + 0x7fffu + ((u >> 16) & 1u)) >> 16;   // RNE
    return (unsigned short)u;
}
__device__ __forceinline__ float bf2f(unsigned short h) {
    return __uint_as_float(((unsigned)h) << 16);
}

__device__ __forceinline__ bf16x8 cvt8(float4 a, float4 b) {
    union { bf16x8 v; __hip_bfloat162 h[4]; } u;
    u.h[0] = __float22bfloat162_rn(make_float2(a.x, a.y));
    u.h[1] = __float22bfloat162_rn(make_float2(a.z, a.w));
    u.h[2] = __float22bfloat162_rn(make_float2(b.x, b.y));
    u.h[3] = __float22bfloat162_rn(make_float2(b.z, b.w));
    return u.v;
}

__device__ __forceinline__ u32x4 pack2(f32x4 x, f32x4 y) {
    union { u32x4 u; __hip_bfloat162 h[4]; } o;
    o.h[0] = __float22bfloat162_rn(make_float2(x[0], x[1]));
    o.h[1] = __float22bfloat162_rn(make_float2(x[2], x[3]));
    o.h[2] = __float22bfloat162_rn(make_float2(y[0], y[1]));
    o.h[3] = __float22bfloat162_rn(make_float2(y[2], y[3]));
    return o.u;
}

// ---------- prep3: zero deg/ovfcnt + featb cast + Wt transpose ----------
// KEEP the staging passes: round-9 A/B (direct fp32 feat/W reads in the
// transform) cost +12us in fused3 (+54MB FETCH: fp32 feat re-reads not
// L3-absorbed; 1.2e7 LDS bank conflicts from in-flight W transpose).
__global__ __launch_bounds__(256) void prep3_kernel(
    const float* __restrict__ feat, unsigned short* __restrict__ featb,
    const float* __restrict__ W, unsigned short* __restrict__ Wt,
    int* __restrict__ deg /* N+1 ints: deg[N] = ovf counter */,
    int N, int fcTotal /*chunks of 8*/, int wtTotal)
{
    int zBlocks  = (N + 1 + 255) >> 8;
    int fcBlocks = (fcTotal + 255) >> 8;
    int b = blockIdx.x;
    if (b < zBlocks) {
        int i = b * 256 + threadIdx.x;
        if (i <= N) deg[i] = 0;
    } else if (b < zBlocks + fcBlocks) {
        int i = (b - zBlocks) * 256 + threadIdx.x;
        if (i < fcTotal) {
            const float4* p = (const float4*)feat + (size_t)i * 2;
            *(bf16x8*)(featb + (size_t)i * 8) = cvt8(p[0], p[1]);
        }
    } else {
        int idx = (b - zBlocks - fcBlocks) * 256 + threadIdx.x;
        if (idx < wtTotal) {
            int r = idx >> 14;
            int rem = idx & 16383;
            int k = rem >> 7, c = rem & 127;
            Wt[(r << 14) + (c << 7) + k] = f2bf(W[idx]);
        }
    }
}

// ---------- fused3: transform + count&slot-write, Bresenham-interleaved ----------
// Champion config (measured best of 10 variants over rounds 0-9): plain slot
// stores, ds=1, 1 edge/thread count, bf16 featb/Wt staging, plain H stores.
// transform: H[r][n][perm(c)] = bf16(featb[n][:] @ W[r]); Wt[rel] in
// XOR-swizzled LDS (one barrier), conflict-free ds_read_b128, permuted
// sector-aligned u32x4 stores. count: ord = atomicAdd(deg[dst]);
// slots[dst*CAP+ord] = H-row byte offset.
__global__ __launch_bounds__(256) void fused3_kernel(
    const unsigned short* __restrict__ featb, const unsigned short* __restrict__ Wt,
    unsigned short* __restrict__ H,
    const int* __restrict__ dst, const int* __restrict__ et,
    const int* __restrict__ src,
    int* __restrict__ deg, unsigned int* __restrict__ slots,
    int* __restrict__ ovf,
    int N, int NBX, int tBlocks, int cntBlocks, int E)
{
    __shared__ __align__(16) unsigned short sW[128 * 128];   // 32 KB
    const int b = blockIdx.x;
    const long long total = (long long)tBlocks + cntBlocks;

    long long cb = ((long long)b * cntBlocks) / total;
    bool isCount = (((long long)(b + 1) * cntBlocks) / total) > cb;

    if (isCount) {
        int e = (int)cb * 256 + threadIdx.x;
        if (e < E) {
            int d = dst[e];
            unsigned key = ((unsigned)et[e] * (unsigned)N + (unsigned)src[e]) << 8;
            int ord = atomicAdd(&deg[d], 1);
            if (ord < CAP) {
                slots[(size_t)d * CAP + ord] = key;
            } else {
                int o = atomicAdd(&deg[N], 1);   // overflow counter
                if (o < OVFCAP) ovf[o] = e;
            }
        }
        return;
    }

    const int tIdx = b - (int)cb;
    const int rel = tIdx / NBX;
    const int bx  = tIdx - rel * NBX;
    const int tid  = threadIdx.x;
    const int wave = tid >> 6, lane = tid & 63;
    const int q    = lane >> 4, mlo = lane & 15;

    // stage Wt[rel] -> LDS, swizzled: row c, 16B chunk ch at (ch ^ (c&15))
    {
        const ulonglong2* wsrc = (const ulonglong2*)(Wt + ((size_t)rel << 14));
        #pragma unroll
        for (int i = 0; i < 8; ++i) {
            int idx = tid + 256 * i;           // 0..2047
            int row = idx >> 4, ch = idx & 15;
            ulonglong2 v = wsrc[idx];
            *(ulonglong2*)&sW[row * 128 + ((ch ^ (row & 15)) * 8)] = v;
        }
    }

    // B-frags: 2 groups of 16 nodes; B[k=ks*32+q*8+j][n=mlo]
    const int nb = bx * 128 + wave * 32;
    bf16x8 bfr[2][4];
    int nodeg[2];
    #pragma unroll
    for (int g = 0; g < 2; ++g) {
        int node = nb + g * 16 + mlo;
        nodeg[g] = node;
        int ld = node < N ? node : N - 1;
        const unsigned short* fp = featb + (size_t)ld * D + q * 8;
        #pragma unroll
        for (int ks = 0; ks < 4; ++ks)
            bfr[g][ks] = *(const bf16x8*)(fp + ks * 32);
    }
    __syncthreads();

    const size_t Hb = (size_t)rel * N * D;
    unsigned short* hp0 = H + Hb + (size_t)nodeg[0] * D + q * 8;
    unsigned short* hp1 = H + Hb + (size_t)nodeg[1] * D + q * 8;

    #pragma unroll
    for (int j = 0; j < 4; ++j) {
        bf16x8 af0[4], af1[4];
        const int row0 = (2 * j) * 16 + mlo, row1 = row0 + 16;
        #pragma unroll
        for (int ks = 0; ks < 4; ++ks) {
            af0[ks] = *(const bf16x8*)&sW[row0 * 128 + (((ks * 4 + q) ^ mlo) * 8)];
            af1[ks] = *(const bf16x8*)&sW[row1 * 128 + (((ks * 4 + q) ^ mlo) * 8)];
        }
        #pragma unroll
        for (int g = 0; g < 2; ++g) {
            f32x4 a = {0.f,0.f,0.f,0.f}, c = {0.f,0.f,0.f,0.f};
            #pragma unroll
            for (int ks = 0; ks < 4; ++ks) {
                a = __builtin_amdgcn_mfma_f32_16x16x32_bf16(af0[ks], bfr[g][ks], a, 0, 0, 0);
                c = __builtin_amdgcn_mfma_f32_16x16x32_bf16(af1[ks], bfr[g][ks], c, 0, 0, 0);
            }
            if (nodeg[g] < N)
                *(u32x4*)((g ? hp1 : hp0) + j * 32) = pack2(a, c);
        }
    }
}

// ---------- gather: 1 node/wave; CAP=32 -> exactly one 16-load batch (loop
// gone). Head loads (feat residual, slots row, deg) issued back-to-back with
// static lane clamp so they resolve in parallel (slots is L2-warm with plain
// stores). 8-B lane loads (32 lanes/row, halves take even/odd edges);
// combine via shfl(lane^32); channel map matches transform's permuted H. ----------
__global__ __launch_bounds__(256) void k_gather6(
    const char* __restrict__ Hc, const unsigned int* __restrict__ slots,
    const int* __restrict__ deg, const float* __restrict__ feat,
    float* __restrict__ out, int N)
{
    int n = blockIdx.x * 4 + (threadIdx.x >> 6);
    if (n >= N) return;
    int lane = threadIdx.x & 63;
    int h = lane >> 5, l5 = lane & 31;

    // --- independent head loads, all issued before any dependent op ---
    const int f4 = 8 * (l5 >> 3) + 4 * (l5 & 1) + ((l5 >> 1) & 3);
    float4 fv = ((const float4*)feat)[(size_t)n * 32 + f4];   // h=1 hits same lines
    unsigned ep = slots[(size_t)n * CAP + (lane < CAP ? lane : CAP - 1)];
    int dg = deg[n];

    dg = __builtin_amdgcn_readfirstlane(dg);
    int capped = dg < CAP ? dg : CAP;

    float2 acc0 = {0.f, 0.f}, acc1 = {0.f, 0.f};

    if (capped > 0) {
        unsigned long long a[16];
        #pragma unroll
        for (int u = 0; u < 16; ++u) {
            int eidx = 2 * u + h;
            int cl = eidx < capped ? eidx : capped - 1;
            unsigned p = __shfl(ep, cl);
            a[u] = *(const unsigned long long*)(Hc + p + l5 * 8);
        }
        #pragma unroll
        for (int u = 0; u < 16; ++u) {
            bool v = (2 * u + h) < capped;
            unsigned lo = (unsigned)a[u], hi = (unsigned)(a[u] >> 32);
            acc0.x += v ? bf2f((unsigned short)(lo & 0xffffu)) : 0.f;
            acc0.y += v ? bf2f((unsigned short)(lo >> 16)) : 0.f;
            acc1.x += v ? bf2f((unsigned short)(hi & 0xffffu)) : 0.f;
            acc1.y += v ? bf2f((unsigned short)(hi >> 16)) : 0.f;
        }
    }
    // combine halves
    acc0.x += __shfl(acc0.x, lane ^ 32);
    acc0.y += __shfl(acc0.y, lane ^ 32);
    acc1.x += __shfl(acc1.x, lane ^ 32);
    acc1.y += __shfl(acc1.y, lane ^ 32);
    if (h == 0) {
        float4 o;
        o.x = fv.x + acc0.x; o.y = fv.y + acc0.y;
        o.z = fv.z + acc1.x; o.w = fv.w + acc1.y;
        ((float4*)out)[(size_t)n * 32 + f4] = o;
    }
}

// ---------- overflow scatter (tiny: deg>CAP nodes only; correctness path) ----------
__global__ __launch_bounds__(256) void k_ovf(
    const char* __restrict__ Hc, const int* __restrict__ ovf,
    const int* __restrict__ deg /* deg[N] = count */,
    const int* __restrict__ dst, const int* __restrict__ et,
    const int* __restrict__ src, float* __restrict__ out, int N)
{
    int cnt = deg[N];
    if (cnt > OVFCAP) cnt = OVFCAP;
    int wid = (blockIdx.x * 256 + threadIdx.x) >> 6;
    int nw = (gridDim.x * 256) >> 6;
    int lane = threadIdx.x & 63;
    const int jj = lane >> 4, qq = (lane >> 2) & 3, pp = lane & 3;
    const int f = 16 * jj + 8 * (pp >> 1) + 2 * qq + (pp & 1);
    for (int i = wid; i < cnt; i += nw) {
        int e = ovf[i];
        int d = dst[e];
        unsigned key = ((unsigned)et[e] * (unsigned)N + (unsigned)src[e]) << 8;
        unsigned a = *(const unsigned*)(Hc + key + lane * 4);
        atomicAdd(out + (size_t)d * D + 2 * f,     bf2f((unsigned short)(a & 0xffffu)));
        atomicAdd(out + (size_t)d * D + 2 * f + 1, bf2f((unsigned short)(a >> 16)));
    }
}

// ---------- fallbacks ----------
__global__ __launch_bounds__(256) void init_kernel(
    const float* __restrict__ feat, float* __restrict__ out, int n4)
{
    int i = blockIdx.x * 256 + threadIdx.x;
    if (i < n4) ((float4*)out)[i] = ((const float4*)feat)[i];
}

__global__ __launch_bounds__(128) void edge_matvec_kernel(
    const float* __restrict__ feat, const float* __restrict__ W,
    const int* __restrict__ et, const int* __restrict__ src,
    const int* __restrict__ dst, float* __restrict__ out, int E)
{
    __shared__ float xs[D];
    int e = blockIdx.x;
    int c = threadIdx.x;
    int s = src[e], r = et[e], d = dst[e];
    xs[c] = feat[(size_t)s * D + c];
    __syncthreads();
    const float* Wr = W + (size_t)r * D * D;
    float acc = 0.f;
    #pragma unroll 8
    for (int k = 0; k < D; ++k) acc += xs[k] * Wr[(size_t)k * D + c];
    atomicAdd(out + (size_t)d * D + c, acc);
}

static inline size_t al256(size_t x) { return (x + 255) & ~(size_t)255; }

extern "C" void kernel_launch(void* const* d_in, const int* in_sizes, int n_in,
                              void* d_out, int out_size, void* d_ws, size_t ws_size,
                              hipStream_t stream) {
    const float* feat = (const float*)d_in[0];
    const float* W    = (const float*)d_in[1];
    const int*   et   = (const int*)d_in[2];
    const int*   src  = (const int*)d_in[3];
    const int*   dst  = (const int*)d_in[4];
    float* out = (float*)d_out;

    const int N = in_sizes[0] / D;
    const int R = in_sizes[1] / (D * D);
    const int E = in_sizes[2];

    size_t hB   = al256((size_t)R * N * D * sizeof(unsigned short));
    size_t wtB  = al256((size_t)R * D * D * sizeof(unsigned short));
    size_t degB = al256((size_t)(N + 1) * sizeof(int));
    size_t sltB = al256((size_t)N * CAP * sizeof(unsigned int));
    size_t ovfB = al256((size_t)OVFCAP * sizeof(int));
    size_t fbB  = al256((size_t)N * D * sizeof(unsigned short));
    size_t need = hB + wtB + degB + sltB + ovfB + fbB;

    const bool packable = ((size_t)R * (size_t)N * 256ull <= 0xFFFFFFFFull);

    if (ws_size >= need && packable) {
        char* p = (char*)d_ws;
        unsigned short* H      = (unsigned short*)p;           p += hB;
        unsigned short* Wt     = (unsigned short*)p;           p += wtB;
        int*            deg    = (int*)p;                      p += degB;
        unsigned int*   slots  = (unsigned int*)p;             p += sltB;
        int*            ovf    = (int*)p;                      p += ovfB;
        unsigned short* featb  = (unsigned short*)p;

        int wtTotal = R * D * D;
        int fcTotal = (N * D) / 8;
        int zBlocks  = (N + 1 + 255) / 256;
        int fcBlocks = (fcTotal + 255) / 256;
        int wtBlocks = (wtTotal + 255) / 256;
        int cntBlocks = (E + 255) / 256;

        prep3_kernel<<<zBlocks + fcBlocks + wtBlocks, 256, 0, stream>>>(
            feat, featb, W, Wt, deg, N, fcTotal, wtTotal);

        int NBX = (N + 127) / 128;
        int tBlocks = NBX * R;
        fused3_kernel<<<tBlocks + cntBlocks, 256, 0, stream>>>(
            featb, Wt, H, dst, et, src, deg, slots, ovf,
            N, NBX, tBlocks, cntBlocks, E);

        k_gather6<<<(N + 3) / 4, 256, 0, stream>>>(
            (const char*)H, slots, deg, feat, out, N);

        k_ovf<<<16, 256, 0, stream>>>(
            (const char*)H, ovf, deg, dst, et, src, out, N);
    } else {
        int n4 = (N * D) / 4;
        init_kernel<<<(n4 + 255) / 256, 256, 0, stream>>>(feat, out, n4);
        edge_matvec_kernel<<<E, 128, 0, stream>>>(feat, W, et, src, dst, out, E);
    }
}

// Round 11
// 166.064 us; speedup vs baseline: 1.0728x; 1.0191x over previous
//
#include <hip/hip_runtime.h>
#include <hip/hip_bf16.h>
#include <stdint.h>

#define D 128
#define CAP 32        // per-node slot capacity; Poisson(12.8): P(deg>32)~1e-6/node,
                      // expected <2 nodes overflow on E=640K -- k_ovf covers them.
#define OVFCAP 65536

using bf16x8 = __attribute__((ext_vector_type(8))) short;
using f32x4  = __attribute__((ext_vector_type(4))) float;
using u32x4  = __attribute__((ext_vector_type(4))) unsigned int;

__device__ __forceinline__ unsigned short f2bf(float f) {
    unsigned u = __float_as_uint(f);
    u = (u + 0x7fffu + ((u >> 16) & 1u)) >> 16;   // RNE
    return (unsigned short)u;
}
__device__ __forceinline__ float bf2f(unsigned short h) {
    return __uint_as_float(((unsigned)h) << 16);
}

__device__ __forceinline__ bf16x8 cvt8(float4 a, float4 b) {
    union { bf16x8 v; __hip_bfloat162 h[4]; } u;
    u.h[0] = __float22bfloat162_rn(make_float2(a.x, a.y));
    u.h[1] = __float22bfloat162_rn(make_float2(a.z, a.w));
    u.h[2] = __float22bfloat162_rn(make_float2(b.x, b.y));
    u.h[3] = __float22bfloat162_rn(make_float2(b.z, b.w));
    return u.v;
}

__device__ __forceinline__ u32x4 pack2(f32x4 x, f32x4 y) {
    union { u32x4 u; __hip_bfloat162 h[4]; } o;
    o.h[0] = __float22bfloat162_rn(make_float2(x[0], x[1]));
    o.h[1] = __float22bfloat162_rn(make_float2(x[2], x[3]));
    o.h[2] = __float22bfloat162_rn(make_float2(y[0], y[1]));
    o.h[3] = __float22bfloat162_rn(make_float2(y[2], y[3]));
    return o.u;
}

// ---------- prep3: zero deg/ovfcnt + featb cast + Wt transpose ----------
// KEEP the staging passes: round-9 A/B (direct fp32 feat/W reads in the
// transform) cost +12us in fused3 (+54MB FETCH: fp32 feat re-reads not
// L3-absorbed; 1.2e7 LDS bank conflicts from in-flight W transpose).
__global__ __launch_bounds__(256) void prep3_kernel(
    const float* __restrict__ feat, unsigned short* __restrict__ featb,
    const float* __restrict__ W, unsigned short* __restrict__ Wt,
    int* __restrict__ deg /* N+1 ints: deg[N] = ovf counter */,
    int N, int fcTotal /*chunks of 8*/, int wtTotal)
{
    int zBlocks  = (N + 1 + 255) >> 8;
    int fcBlocks = (fcTotal + 255) >> 8;
    int b = blockIdx.x;
    if (b < zBlocks) {
        int i = b * 256 + threadIdx.x;
        if (i <= N) deg[i] = 0;
    } else if (b < zBlocks + fcBlocks) {
        int i = (b - zBlocks) * 256 + threadIdx.x;
        if (i < fcTotal) {
            const float4* p = (const float4*)feat + (size_t)i * 2;
            *(bf16x8*)(featb + (size_t)i * 8) = cvt8(p[0], p[1]);
        }
    } else {
        int idx = (b - zBlocks - fcBlocks) * 256 + threadIdx.x;
        if (idx < wtTotal) {
            int r = idx >> 14;
            int rem = idx & 16383;
            int k = rem >> 7, c = rem & 127;
            Wt[(r << 14) + (c << 7) + k] = f2bf(W[idx]);
        }
    }
}

// ---------- fused3: transform + count&slot-write, Bresenham-interleaved ----------
// Champion config (measured best of 11 variants over rounds 0-10): plain slot
// stores, ds=1, 1 edge/thread count, bf16 featb/Wt staging, plain H stores.
// transform: H[r][n][perm(c)] = bf16(featb[n][:] @ W[r]); Wt[rel] in
// XOR-swizzled LDS (one barrier), conflict-free ds_read_b128, permuted
// sector-aligned u32x4 stores. count: ord = atomicAdd(deg[dst]);
// slots[dst*CAP+ord] = H-row byte offset.
__global__ __launch_bounds__(256) void fused3_kernel(
    const unsigned short* __restrict__ featb, const unsigned short* __restrict__ Wt,
    unsigned short* __restrict__ H,
    const int* __restrict__ dst, const int* __restrict__ et,
    const int* __restrict__ src,
    int* __restrict__ deg, unsigned int* __restrict__ slots,
    int* __restrict__ ovf,
    int N, int NBX, int tBlocks, int cntBlocks, int E)
{
    __shared__ __align__(16) unsigned short sW[128 * 128];   // 32 KB
    const int b = blockIdx.x;
    const long long total = (long long)tBlocks + cntBlocks;

    long long cb = ((long long)b * cntBlocks) / total;
    bool isCount = (((long long)(b + 1) * cntBlocks) / total) > cb;

    if (isCount) {
        int e = (int)cb * 256 + threadIdx.x;
        if (e < E) {
            int d = dst[e];
            unsigned key = ((unsigned)et[e] * (unsigned)N + (unsigned)src[e]) << 8;
            int ord = atomicAdd(&deg[d], 1);
            if (ord < CAP) {
                slots[(size_t)d * CAP + ord] = key;
            } else {
                int o = atomicAdd(&deg[N], 1);   // overflow counter
                if (o < OVFCAP) ovf[o] = e;
            }
        }
        return;
    }

    const int tIdx = b - (int)cb;
    const int rel = tIdx / NBX;
    const int bx  = tIdx - rel * NBX;
    const int tid  = threadIdx.x;
    const int wave = tid >> 6, lane = tid & 63;
    const int q    = lane >> 4, mlo = lane & 15;

    // stage Wt[rel] -> LDS, swizzled: row c, 16B chunk ch at (ch ^ (c&15))
    {
        const ulonglong2* wsrc = (const ulonglong2*)(Wt + ((size_t)rel << 14));
        #pragma unroll
        for (int i = 0; i < 8; ++i) {
            int idx = tid + 256 * i;           // 0..2047
            int row = idx >> 4, ch = idx & 15;
            ulonglong2 v = wsrc[idx];
            *(ulonglong2*)&sW[row * 128 + ((ch ^ (row & 15)) * 8)] = v;
        }
    }

    // B-frags: 2 groups of 16 nodes; B[k=ks*32+q*8+j][n=mlo]
    const int nb = bx * 128 + wave * 32;
    bf16x8 bfr[2][4];
    int nodeg[2];
    #pragma unroll
    for (int g = 0; g < 2; ++g) {
        int node = nb + g * 16 + mlo;
        nodeg[g] = node;
        int ld = node < N ? node : N - 1;
        const unsigned short* fp = featb + (size_t)ld * D + q * 8;
        #pragma unroll
        for (int ks = 0; ks < 4; ++ks)
            bfr[g][ks] = *(const bf16x8*)(fp + ks * 32);
    }
    __syncthreads();

    const size_t Hb = (size_t)rel * N * D;
    unsigned short* hp0 = H + Hb + (size_t)nodeg[0] * D + q * 8;
    unsigned short* hp1 = H + Hb + (size_t)nodeg[1] * D + q * 8;

    #pragma unroll
    for (int j = 0; j < 4; ++j) {
        bf16x8 af0[4], af1[4];
        const int row0 = (2 * j) * 16 + mlo, row1 = row0 + 16;
        #pragma unroll
        for (int ks = 0; ks < 4; ++ks) {
            af0[ks] = *(const bf16x8*)&sW[row0 * 128 + (((ks * 4 + q) ^ mlo) * 8)];
            af1[ks] = *(const bf16x8*)&sW[row1 * 128 + (((ks * 4 + q) ^ mlo) * 8)];
        }
        #pragma unroll
        for (int g = 0; g < 2; ++g) {
            f32x4 a = {0.f,0.f,0.f,0.f}, c = {0.f,0.f,0.f,0.f};
            #pragma unroll
            for (int ks = 0; ks < 4; ++ks) {
                a = __builtin_amdgcn_mfma_f32_16x16x32_bf16(af0[ks], bfr[g][ks], a, 0, 0, 0);
                c = __builtin_amdgcn_mfma_f32_16x16x32_bf16(af1[ks], bfr[g][ks], c, 0, 0, 0);
            }
            if (nodeg[g] < N)
                *(u32x4*)((g ? hp1 : hp0) + j * 32) = pack2(a, c);
        }
    }
}

// ---------- gather: 1 node/wave; degree-adaptive batches (round-11): the
// static 16-u batch issued 32 row-reads/node regardless of deg (mean 12.8)
// -- clamped lanes re-read row capped-1, 2.5x transaction overissue (L2
// hits, invisible in HBM counters but consuming VMEM/L2 slots). Now: first
// 8 u's (16 edges, covers 85% of nodes) always; second 8 u's behind the
// wave-uniform capped>16 branch. Skipped terms were v-masked zeros ->
// numerics identical. Head loads (feat residual, slots row, deg) issued
// back-to-back; 8-B lane loads (32 lanes/row, halves take even/odd edges);
// combine via shfl(lane^32); channel map matches transform's permuted H. ----------
__global__ __launch_bounds__(256) void k_gather6(
    const char* __restrict__ Hc, const unsigned int* __restrict__ slots,
    const int* __restrict__ deg, const float* __restrict__ feat,
    float* __restrict__ out, int N)
{
    int n = blockIdx.x * 4 + (threadIdx.x >> 6);
    if (n >= N) return;
    int lane = threadIdx.x & 63;
    int h = lane >> 5, l5 = lane & 31;

    // --- independent head loads, all issued before any dependent op ---
    const int f4 = 8 * (l5 >> 3) + 4 * (l5 & 1) + ((l5 >> 1) & 3);
    float4 fv = ((const float4*)feat)[(size_t)n * 32 + f4];   // h=1 hits same lines
    unsigned ep = slots[(size_t)n * CAP + (lane < CAP ? lane : CAP - 1)];
    int dg = deg[n];

    dg = __builtin_amdgcn_readfirstlane(dg);
    int capped = dg < CAP ? dg : CAP;

    float2 acc0 = {0.f, 0.f}, acc1 = {0.f, 0.f};

    if (capped > 0) {
        // batch 1: edges 0..15 (u = 0..7)
        unsigned long long a[8];
        #pragma unroll
        for (int u = 0; u < 8; ++u) {
            int eidx = 2 * u + h;
            int cl = eidx < capped ? eidx : capped - 1;
            unsigned p = __shfl(ep, cl);
            a[u] = *(const unsigned long long*)(Hc + p + l5 * 8);
        }
        #pragma unroll
        for (int u = 0; u < 8; ++u) {
            bool v = (2 * u + h) < capped;
            unsigned lo = (unsigned)a[u], hi = (unsigned)(a[u] >> 32);
            acc0.x += v ? bf2f((unsigned short)(lo & 0xffffu)) : 0.f;
            acc0.y += v ? bf2f((unsigned short)(lo >> 16)) : 0.f;
            acc1.x += v ? bf2f((unsigned short)(hi & 0xffffu)) : 0.f;
            acc1.y += v ? bf2f((unsigned short)(hi >> 16)) : 0.f;
        }
        // batch 2: edges 16..31 (u = 8..15), wave-uniform skip for deg<=16
        if (capped > 16) {
            unsigned long long b[8];
            #pragma unroll
            for (int u = 8; u < 16; ++u) {
                int eidx = 2 * u + h;
                int cl = eidx < capped ? eidx : capped - 1;
                unsigned p = __shfl(ep, cl);
                b[u - 8] = *(const unsigned long long*)(Hc + p + l5 * 8);
            }
            #pragma unroll
            for (int u = 8; u < 16; ++u) {
                bool v = (2 * u + h) < capped;
                unsigned lo = (unsigned)b[u - 8], hi = (unsigned)(b[u - 8] >> 32);
                acc0.x += v ? bf2f((unsigned short)(lo & 0xffffu)) : 0.f;
                acc0.y += v ? bf2f((unsigned short)(lo >> 16)) : 0.f;
                acc1.x += v ? bf2f((unsigned short)(hi & 0xffffu)) : 0.f;
                acc1.y += v ? bf2f((unsigned short)(hi >> 16)) : 0.f;
            }
        }
    }
    // combine halves
    acc0.x += __shfl(acc0.x, lane ^ 32);
    acc0.y += __shfl(acc0.y, lane ^ 32);
    acc1.x += __shfl(acc1.x, lane ^ 32);
    acc1.y += __shfl(acc1.y, lane ^ 32);
    if (h == 0) {
        float4 o;
        o.x = fv.x + acc0.x; o.y = fv.y + acc0.y;
        o.z = fv.z + acc1.x; o.w = fv.w + acc1.y;
        ((float4*)out)[(size_t)n * 32 + f4] = o;
    }
}

// ---------- overflow scatter (tiny: deg>CAP nodes only; correctness path) ----------
__global__ __launch_bounds__(256) void k_ovf(
    const char* __restrict__ Hc, const int* __restrict__ ovf,
    const int* __restrict__ deg /* deg[N] = count */,
    const int* __restrict__ dst, const int* __restrict__ et,
    const int* __restrict__ src, float* __restrict__ out, int N)
{
    int cnt = deg[N];
    if (cnt > OVFCAP) cnt = OVFCAP;
    int wid = (blockIdx.x * 256 + threadIdx.x) >> 6;
    int nw = (gridDim.x * 256) >> 6;
    int lane = threadIdx.x & 63;
    const int jj = lane >> 4, qq = (lane >> 2) & 3, pp = lane & 3;
    const int f = 16 * jj + 8 * (pp >> 1) + 2 * qq + (pp & 1);
    for (int i = wid; i < cnt; i += nw) {
        int e = ovf[i];
        int d = dst[e];
        unsigned key = ((unsigned)et[e] * (unsigned)N + (unsigned)src[e]) << 8;
        unsigned a = *(const unsigned*)(Hc + key + lane * 4);
        atomicAdd(out + (size_t)d * D + 2 * f,     bf2f((unsigned short)(a & 0xffffu)));
        atomicAdd(out + (size_t)d * D + 2 * f + 1, bf2f((unsigned short)(a >> 16)));
    }
}

// ---------- fallbacks ----------
__global__ __launch_bounds__(256) void init_kernel(
    const float* __restrict__ feat, float* __restrict__ out, int n4)
{
    int i = blockIdx.x * 256 + threadIdx.x;
    if (i < n4) ((float4*)out)[i] = ((const float4*)feat)[i];
}

__global__ __launch_bounds__(128) void edge_matvec_kernel(
    const float* __restrict__ feat, const float* __restrict__ W,
    const int* __restrict__ et, const int* __restrict__ src,
    const int* __restrict__ dst, float* __restrict__ out, int E)
{
    __shared__ float xs[D];
    int e = blockIdx.x;
    int c = threadIdx.x;
    int s = src[e], r = et[e], d = dst[e];
    xs[c] = feat[(size_t)s * D + c];
    __syncthreads();
    const float* Wr = W + (size_t)r * D * D;
    float acc = 0.f;
    #pragma unroll 8
    for (int k = 0; k < D; ++k) acc += xs[k] * Wr[(size_t)k * D + c];
    atomicAdd(out + (size_t)d * D + c, acc);
}

static inline size_t al256(size_t x) { return (x + 255) & ~(size_t)255; }

extern "C" void kernel_launch(void* const* d_in, const int* in_sizes, int n_in,
                              void* d_out, int out_size, void* d_ws, size_t ws_size,
                              hipStream_t stream) {
    const float* feat = (const float*)d_in[0];
    const float* W    = (const float*)d_in[1];
    const int*   et   = (const int*)d_in[2];
    const int*   src  = (const int*)d_in[3];
    const int*   dst  = (const int*)d_in[4];
    float* out = (float*)d_out;

    const int N = in_sizes[0] / D;
    const int R = in_sizes[1] / (D * D);
    const int E = in_sizes[2];

    size_t hB   = al256((size_t)R * N * D * sizeof(unsigned short));
    size_t wtB  = al256((size_t)R * D * D * sizeof(unsigned short));
    size_t degB = al256((size_t)(N + 1) * sizeof(int));
    size_t sltB = al256((size_t)N * CAP * sizeof(unsigned int));
    size_t ovfB = al256((size_t)OVFCAP * sizeof(int));
    size_t fbB  = al256((size_t)N * D * sizeof(unsigned short));
    size_t need = hB + wtB + degB + sltB + ovfB + fbB;

    const bool packable = ((size_t)R * (size_t)N * 256ull <= 0xFFFFFFFFull);

    if (ws_size >= need && packable) {
        char* p = (char*)d_ws;
        unsigned short* H      = (unsigned short*)p;           p += hB;
        unsigned short* Wt     = (unsigned short*)p;           p += wtB;
        int*            deg    = (int*)p;                      p += degB;
        unsigned int*   slots  = (unsigned int*)p;             p += sltB;
        int*            ovf    = (int*)p;                      p += ovfB;
        unsigned short* featb  = (unsigned short*)p;

        int wtTotal = R * D * D;
        int fcTotal = (N * D) / 8;
        int zBlocks  = (N + 1 + 255) / 256;
        int fcBlocks = (fcTotal + 255) / 256;
        int wtBlocks = (wtTotal + 255) / 256;
        int cntBlocks = (E + 255) / 256;

        prep3_kernel<<<zBlocks + fcBlocks + wtBlocks, 256, 0, stream>>>(
            feat, featb, W, Wt, deg, N, fcTotal, wtTotal);

        int NBX = (N + 127) / 128;
        int tBlocks = NBX * R;
        fused3_kernel<<<tBlocks + cntBlocks, 256, 0, stream>>>(
            featb, Wt, H, dst, et, src, deg, slots, ovf,
            N, NBX, tBlocks, cntBlocks, E);

        k_gather6<<<(N + 3) / 4, 256, 0, stream>>>(
            (const char*)H, slots, deg, feat, out, N);

        k_ovf<<<16, 256, 0, stream>>>(
            (const char*)H, ovf, deg, dst, et, src, out, N);
    } else {
        int n4 = (N * D) / 4;
        init_kernel<<<(n4 + 255) / 256, 256, 0, stream>>>(feat, out, n4);
        edge_matvec_kernel<<<E, 128, 0, stream>>>(feat, W, et, src, dst, out, E);
    }
}